// Round 2
// baseline (794.420 us; speedup 1.0000x reference)
//
#include <hip/hip_runtime.h>

// Encoder: embed -> fused 2-dir input GEMMs (bf16 MFMA, bias folded, gate-interleaved)
//          -> 4x LSTM scan (SINGLE-WG recurrence, 1024-thr WG = 16 waves @ 4 waves/SIMD:
//             Whh as i8 row-scaled register-resident B-frags, 16 units/wave => Bq=64 regs
//             (AGPR), fits the 128-reg cap; h via double-buffered LDS, ONE barrier/step,
//             Hout stored direct from registers)
//          -> co-attention + output head.
// Sizes: V=100000 E=300 H=256 OUT=3 B=128 LS=128 LT=8

typedef unsigned short u16;
typedef unsigned long long u64;
typedef float f32x4 __attribute__((ext_vector_type(4)));
typedef int   i32x4 __attribute__((ext_vector_type(4)));
typedef short bf16x8 __attribute__((ext_vector_type(8)));
typedef short s16x4 __attribute__((ext_vector_type(4)));

#define KP 320   // E=300 padded to mult of 32
#define FH 1024  // 4*H
#define HH 256   // H

struct Ptr4 { const float* p[4]; };

static __device__ __forceinline__ u16 f2bf(float f) {
    unsigned int u = __float_as_uint(f);
    u += 0x7FFFu + ((u >> 16) & 1u);          // RNE
    return (u16)(u >> 16);
}
static __device__ __forceinline__ float bf2f(u16 s) {
    return __uint_as_float((unsigned int)s << 16);
}
static __device__ __forceinline__ float sigm(float x) {
    return __builtin_amdgcn_rcpf(1.0f + __expf(-x));
}
static __device__ __forceinline__ float tanh_(float x) {
    return 1.0f - 2.0f * __builtin_amdgcn_rcpf(1.0f + __expf(2.0f * x));
}

// ---------------------------------------------------------------- embedding
__global__ void embed_kernel(const int* __restrict__ sen, const int* __restrict__ tgt,
                             const float* __restrict__ emb,
                             u16* __restrict__ Xs, u16* __restrict__ Xt)
{
    int row = blockIdx.x;
    int tok; u16* dst;
    if (row < 16384) { tok = sen[row]; dst = Xs + (size_t)row * KP; }
    else             { tok = tgt[row - 16384]; dst = Xt + (size_t)(row - 16384) * KP; }
    const float* src = emb + (size_t)tok * 300;
    for (int k = threadIdx.x; k < KP; k += blockDim.x) {
        float v = (k < 300 && tok != 0) ? src[k] : 0.0f;   // padding_idx=0
        dst[k] = f2bf(v);
    }
}

// ---------------------------------------------------------------- weight prep (all 4 dirs)
__global__ __launch_bounds__(256) void prep_weights_kernel(
    Ptr4 Wih, Ptr4 bih, Ptr4 bhh, u16* __restrict__ WihB, float* __restrict__ biasB)
{
    int dir = blockIdx.y;
    int idx = blockIdx.x * 256 + threadIdx.x;
    if (idx < FH * KP) {
        int row = idx / KP, k = idx - row * KP;
        WihB[(size_t)dir * FH * KP + idx] = (k < 300) ? f2bf(Wih.p[dir][row * 300 + k]) : (u16)0;
    }
    if (idx < FH) biasB[dir * FH + idx] = bih.p[dir][idx] + bhh.p[dir][idx];
}

// ---------------------------------------------------------------- Whh -> i8 row-scaled (all dirs)
__global__ __launch_bounds__(64) void whh_quant_kernel(
    Ptr4 Whh, char* __restrict__ Wq, float* __restrict__ wdq)
{
    int dir = blockIdx.y, row = blockIdx.x, tid = threadIdx.x;
    const float* src = Whh.p[dir] + (size_t)row * HH;
    float m = 0.0f;
    for (int k = tid; k < HH; k += 64) m = fmaxf(m, fabsf(src[k]));
    for (int off = 32; off; off >>= 1) m = fmaxf(m, __shfl_down(m, off));
    m = __shfl(m, 0);
    float qs = (m > 0.0f) ? 127.0f / m : 0.0f;
    char* dst = Wq + (size_t)dir * FH * HH + (size_t)row * HH;
    for (int k = tid; k < HH; k += 64) dst[k] = (char)(int)rintf(src[k] * qs);
    if (tid == 0) wdq[dir * FH + row] = (m > 0.0f) ? m / (127.0f * 127.0f) : 0.0f;
}

// ---------------------------------------------------------------- input GEMM (fused dir-pair)
// One launch covers TWO directions: W has 2048 rows (dir-major), N=2048, NB=32 n-blocks.
// 1D grid, bijective XCD swizzle so each XCD owns a contiguous m-range: the 1.3MB B panel
// stays L2-resident per XCD, A is streamed once. G layout out: [row m][unit*4+gate] bf16.
__global__ __launch_bounds__(256) void input_gemm_kernel(
    const u16* __restrict__ X, const u16* __restrict__ W,
    const float* __restrict__ bias, u16* __restrict__ G, size_t dirStride)
{
    int nwg = gridDim.x;                       // multiple of 8
    int cpx = nwg >> 3;
    int wid = (blockIdx.x & 7) * cpx + (blockIdx.x >> 3);
    int nblk = wid & 31;                       // NB = 32 (N = 2048)
    int mblk = wid >> 5;

    int wave = threadIdx.x >> 6, lane = threadIdx.x & 63;
    int r = lane & 15, quad = lane >> 4;
    int m0 = mblk * 64 + wave * 16;
    int n0 = nblk * 64;
    f32x4 acc[4] = {};
    const u16* xr = X + (size_t)(m0 + r) * KP + quad * 8;
    const u16* wr = W + (size_t)(n0 + r) * KP + quad * 8;
#pragma unroll
    for (int k0 = 0; k0 < KP; k0 += 32) {
        bf16x8 a = *(const bf16x8*)(xr + k0);
#pragma unroll
        for (int j = 0; j < 4; ++j) {
            bf16x8 b = *(const bf16x8*)(wr + (size_t)j * 16 * KP + k0);
            acc[j] = __builtin_amdgcn_mfma_f32_16x16x32_bf16(a, b, acc[j], 0, 0, 0);
        }
    }
#pragma unroll
    for (int j = 0; j < 4; ++j)
#pragma unroll
        for (int reg = 0; reg < 4; ++reg) {
            int row = quad * 4 + reg;
            int n = n0 + j * 16 + r;           // global col in [0,2048)
            int dirb = n >> 10, nn = n & 1023;
            int gate = nn >> 8, unit = nn & 255;
            G[(size_t)dirb * dirStride + (size_t)(m0 + row) * FH + unit * 4 + gate]
                = f2bf(acc[j][reg] + bias[n]);
        }
}

// ---------------------------------------------------------------- LSTM scan
// 32 WGs x 1024 thr (16 waves; a 1024-thr WG forces 4 waves/SIMD => 128-reg cap).
// dir = bx>>3, batch chunk = (bx&7)*16. ONE WG holds the entire direction recurrence
// for its 16 batches. Wave w owns units [w*16,w*16+16) x 4 gates = 64 Whh rows:
// Bq[4][8] u64 = 64 regs/lane of i8 B-frags (compiler puts these in AGPRs — MFMA reads
// B straight from AGPR, free; R1's 512-thr variant showed VGPR=116 + Bq in AGPRs).
// Step-loop live VGPRs ~50 => ~114/128 total. 2->4 waves/SIMD attacks the ~3000 cy/step
// of exposed latency R1's counters showed (active-CU VALUBusy 33%, MfmaUtil 17%).
// h double-buffered in LDS: MFMA reads hb8[s&1], gates write hb8[s&1^1] => ONE
// __syncthreads per step (R1 had two). Hout written direct from registers (64B segments),
// hbf staging deleted. All register arrays statically indexed.
// mfma_i32_16x16x32_i8: A lane(m=l&15,k=quad*8+j), B lane(n=l&15,k=quad*8+j),
// D lane(col=l&15,row=quad*4+reg) — all 4 gates of a unit land in one lane.
__global__ __launch_bounds__(1024, 1) void lstm_scan_kernel(
    const char*  __restrict__ WqB,   // [4][1024][256] i8
    const float* __restrict__ wdq,   // [4][1024] dequant scales
    const u16*   __restrict__ Gs,    // [2][16384][1024] bf16 (gate-interleaved, bias folded)
    const u16*   __restrict__ Gt,    // [2][1024][1024] bf16
    float* __restrict__ senH,        // [128][128][512]
    float* __restrict__ tgtH)        // [128][8][512]
{
    const int bx  = blockIdx.x;
    const int dir = bx >> 3;
    const int b0  = (bx & 7) << 4;
    const int T   = (dir < 2) ? 128 : 8;
    const int rev = dir & 1;

    const char* Wq = WqB + (size_t)dir * FH * HH;
    const u16*  G  = (dir < 2) ? (Gs + (size_t)dir * 16384 * FH)
                               : (Gt + (size_t)(dir - 2) * 1024 * FH);
    float* Hout = (dir < 2) ? senH : tgtH;
    const int hofs = rev ? 256 : 0;

    const int tid  = threadIdx.x;
    const int w    = tid >> 6, lane = tid & 63;
    const int r    = lane & 15, quad = lane >> 4;
    const int u    = w * 16 + r;     // this lane's unit

    __shared__ char hb8[2][16][272]; // h as i8, double-buffered (A-operand source)

    // ---- Whh i8 B-frags into registers (persist across all steps)
    // Bq[g][kt]: row = g*256 + u, k-slice = kt*32 + quad*8
    u64 Bq[4][8];
    float dqv[4];
#pragma unroll
    for (int g = 0; g < 4; ++g) {
        int row = g * 256 + u;
        dqv[g] = wdq[dir * FH + row];
#pragma unroll
        for (int kt = 0; kt < 8; ++kt)
            Bq[g][kt] = *(const u64*)(Wq + ((size_t)row << 8) + kt * 32 + quad * 8);
    }

    // ---- zero h(-1) (buffer 0; buffer 1 is written before first read)
    for (int i = tid; i < 2 * 16 * 272; i += 1024) (&hb8[0][0][0])[i] = 0;
    __syncthreads();

    float c[4] = {};   // cell state per batch-row reg

    for (int s = 0; s < T; ++s) {
        const int t   = rev ? (T - 1 - s) : s;
        const int cur = s & 1;

        // ---- pregates for this step (independent of h; latency hides under MFMA)
        s16x4 gv[4];
#pragma unroll
        for (int reg = 0; reg < 4; ++reg)
            gv[reg] = *(const s16x4*)(G + ((size_t)(b0 + quad * 4 + reg) * T + t) * FH
                                      + u * 4);

        // ---- recurrent matmul: 32 i8 MFMAs/wave (x16 waves), A from hb8[cur]
        i32x4 acc[4] = {};   // per gate
#pragma unroll
        for (int kt = 0; kt < 8; ++kt) {
            u64 a = *(const u64*)&hb8[cur][r][quad * 8 + kt * 32];
#pragma unroll
            for (int g = 0; g < 4; ++g)
                acc[g] = __builtin_amdgcn_mfma_i32_16x16x32_i8(
                    (long long)a, (long long)Bq[g][kt], acc[g], 0, 0, 0);
        }

        // ---- gates -> c,h ; h(s) -> hb8[cur^1] (i8) + Hout direct
#pragma unroll
        for (int reg = 0; reg < 4; ++reg) {
            int bb = quad * 4 + reg;
            float pi = (float)acc[0][reg] * dqv[0] + bf2f((u16)gv[reg].x);
            float pf = (float)acc[1][reg] * dqv[1] + bf2f((u16)gv[reg].y);
            float pg = (float)acc[2][reg] * dqv[2] + bf2f((u16)gv[reg].z);
            float po = (float)acc[3][reg] * dqv[3] + bf2f((u16)gv[reg].w);
            float ig = sigm(pi), fg = sigm(pf), gg = tanh_(pg), og = sigm(po);
            float cn = fg * c[reg] + ig * gg;
            c[reg] = cn;
            float hn = og * tanh_(cn);
            hb8[cur ^ 1][bb][u] = (char)(int)rintf(hn * 127.0f);
            Hout[((size_t)(b0 + bb) * T + t) * 512 + hofs + u] = hn;
        }
        __syncthreads();   // h(s) visible; next region may overwrite hb8[cur]
    }
}

// ---------------------------------------------------------------- attention + head
__global__ __launch_bounds__(256) void attn_out_kernel(
    const float* __restrict__ senH, const float* __restrict__ tgtH,
    const float* __restrict__ Wout, const float* __restrict__ bout,
    float* __restrict__ out)
{
    int b = blockIdx.x, tid = threadIdx.x;
    __shared__ float tg[8][512];
    __shared__ float Am[128][9];
    __shared__ float rowm[128][9];
    __shared__ float mcol[8], csum[8], rvec[8], attn[128], score[512], lg[3];

    const float* tgg = tgtH + (size_t)b * 8 * 512;
    for (int i = tid; i < 4096; i += 256) tg[i >> 9][i & 511] = tgg[i];
    __syncthreads();

    {   // A[s][t] = sen_h[b,s,:] . tgt_h[b,t,:]
        int s = tid >> 1, t0 = (tid & 1) * 4;
        const float* sr = senH + ((size_t)b * 128 + s) * 512;
        float d0 = 0, d1 = 0, d2 = 0, d3 = 0;
        for (int h = 0; h < 512; ++h) {
            float x = sr[h];
            d0 += x * tg[t0 + 0][h]; d1 += x * tg[t0 + 1][h];
            d2 += x * tg[t0 + 2][h]; d3 += x * tg[t0 + 3][h];
        }
        Am[s][t0 + 0] = d0; Am[s][t0 + 1] = d1; Am[s][t0 + 2] = d2; Am[s][t0 + 3] = d3;
    }
    __syncthreads();

    if (tid < 8) {  // col-softmax stats over s, per t
        float m = -1e30f;
        for (int s = 0; s < 128; ++s) m = fmaxf(m, Am[s][tid]);
        float sum = 0;
        for (int s = 0; s < 128; ++s) sum += __expf(Am[s][tid] - m);
        mcol[tid] = m; csum[tid] = sum;
    }
    if (tid >= 64 && tid < 192) {  // row softmax per s
        int s = tid - 64;
        float m = -1e30f;
        for (int t = 0; t < 8; ++t) m = fmaxf(m, Am[s][t]);
        float e[8], sum = 0;
        for (int t = 0; t < 8; ++t) { e[t] = __expf(Am[s][t] - m); sum += e[t]; }
        float inv = __builtin_amdgcn_rcpf(sum);
        for (int t = 0; t < 8; ++t) rowm[s][t] = e[t] * inv;
    }
    __syncthreads();
    if (tid < 8) {
        float sum = 0;
        for (int s = 0; s < 128; ++s) sum += rowm[s][tid];
        rvec[tid] = sum * (1.0f / 128.0f);
    }
    __syncthreads();
    if (tid < 128) {
        float a = 0;
        for (int t = 0; t < 8; ++t)
            a += __expf(Am[tid][t] - mcol[t]) / csum[t] * rvec[t];
        attn[tid] = a;
    }
    __syncthreads();
    for (int h = tid; h < 512; h += 256) {
        float acc = 0;
        const float* sp = senH + (size_t)b * 128 * 512 + h;
        for (int s = 0; s < 128; ++s) acc += attn[s] * sp[(size_t)s * 512];
        score[h] = acc;
    }
    __syncthreads();
    if (tid < 3) {
        float acc = bout[tid];
        const float* wr = Wout + tid * 512;
        for (int h = 0; h < 512; ++h) acc += score[h] * wr[h];
        lg[tid] = acc;
    }
    __syncthreads();
    if (tid == 0) {
        float m = fmaxf(lg[0], fmaxf(lg[1], lg[2]));
        float e0 = __expf(lg[0] - m), e1 = __expf(lg[1] - m), e2 = __expf(lg[2] - m);
        float inv = 1.0f / (e0 + e1 + e2);
        out[b * 3 + 0] = e0 * inv; out[b * 3 + 1] = e1 * inv; out[b * 3 + 2] = e2 * inv;
    }
}

// ---------------------------------------------------------------- launch
extern "C" void kernel_launch(void* const* d_in, const int* in_sizes, int n_in,
                              void* d_out, int out_size, void* d_ws, size_t ws_size,
                              hipStream_t stream)
{
    const int*   sen = (const int*)d_in[0];
    const int*   tgt = (const int*)d_in[1];
    const float* emb = (const float*)d_in[2];
    Ptr4 Wih = {{(const float*)d_in[3],  (const float*)d_in[7],
                 (const float*)d_in[11], (const float*)d_in[15]}};
    Ptr4 Whh = {{(const float*)d_in[4],  (const float*)d_in[8],
                 (const float*)d_in[12], (const float*)d_in[16]}};
    Ptr4 bih = {{(const float*)d_in[5],  (const float*)d_in[9],
                 (const float*)d_in[13], (const float*)d_in[17]}};
    Ptr4 bhh = {{(const float*)d_in[6],  (const float*)d_in[10],
                 (const float*)d_in[14], (const float*)d_in[18]}};
    const float* Wout = (const float*)d_in[19];
    const float* bout = (const float*)d_in[20];
    float* out = (float*)d_out;

    char* ws = (char*)d_ws;
    size_t off = 0;
    auto alloc = [&](size_t bytes) -> void* {
        void* p = ws + off; off += (bytes + 255) & ~(size_t)255; return p;
    };
    u16*   Xs    = (u16*)alloc((size_t)16384 * KP * 2);
    u16*   Xt    = (u16*)alloc((size_t)1024 * KP * 2);
    u16*   WihB  = (u16*)alloc((size_t)4 * FH * KP * 2);
    char*  WqB   = (char*)alloc((size_t)4 * FH * HH);
    float* wdq   = (float*)alloc((size_t)4 * FH * 4);
    float* biasB = (float*)alloc((size_t)4 * FH * 4);
    u16*   Gs    = (u16*)alloc((size_t)2 * 16384 * FH * 2);
    u16*   Gt    = (u16*)alloc((size_t)2 * 1024 * FH * 2);
    float* senH  = (float*)alloc((size_t)128 * 128 * 512 * 4);
    float* tgtH  = (float*)alloc((size_t)128 * 8 * 512 * 4);
    (void)ws_size; (void)in_sizes; (void)n_in; (void)out_size;

    embed_kernel<<<17408, 128, 0, stream>>>(sen, tgt, emb, Xs, Xt);
    prep_weights_kernel<<<dim3(1280, 4), 256, 0, stream>>>(Wih, bih, bhh, WihB, biasB);
    whh_quant_kernel<<<dim3(FH, 4), 64, 0, stream>>>(Whh, WqB, wdq);

    // sen: M=16384, N=2048 (dirs 0,1). tgt: M=1024, N=2048 (dirs 2,3).
    input_gemm_kernel<<<8192, 256, 0, stream>>>(Xs, WihB, biasB, Gs,
                                                (size_t)16384 * FH);
    input_gemm_kernel<<<512, 256, 0, stream>>>(Xt, WihB + (size_t)2 * FH * KP,
                                               biasB + 2 * FH, Gt,
                                               (size_t)1024 * FH);

    lstm_scan_kernel<<<32, 1024, 0, stream>>>(WqB, wdq, Gs, Gt, senH, tgtH);
    attn_out_kernel<<<128, 256, 0, stream>>>(senH, tgtH, Wout, bout, out);
}

// Round 3
// 739.664 us; speedup vs baseline: 1.0740x; 1.0740x over previous
//
#include <hip/hip_runtime.h>

// Encoder: embed -> fused 2-dir input GEMMs (bf16 MFMA, bias folded, gate-interleaved)
//          -> 4x LSTM scan (SINGLE-WG recurrence, 1024-thr WG = 16 waves @ 4 waves/SIMD,
//             Whh as i8 row-scaled register-resident B-frags (AGPR), h double-buffered in
//             LDS, ONE barrier/step, and VMEM software-pipelined one full step:
//             gv(s+1) prefetched + h(s-1) stored at the TOP of step s so the compiler's
//             vmcnt(0)-before-s_barrier drain is free)
//          -> co-attention + output head.
// Sizes: V=100000 E=300 H=256 OUT=3 B=128 LS=128 LT=8

typedef unsigned short u16;
typedef unsigned long long u64;
typedef float f32x4 __attribute__((ext_vector_type(4)));
typedef int   i32x4 __attribute__((ext_vector_type(4)));
typedef short bf16x8 __attribute__((ext_vector_type(8)));
typedef short s16x4 __attribute__((ext_vector_type(4)));

#define KP 320   // E=300 padded to mult of 32
#define FH 1024  // 4*H
#define HH 256   // H

struct Ptr4 { const float* p[4]; };

static __device__ __forceinline__ u16 f2bf(float f) {
    unsigned int u = __float_as_uint(f);
    u += 0x7FFFu + ((u >> 16) & 1u);          // RNE
    return (u16)(u >> 16);
}
static __device__ __forceinline__ float bf2f(u16 s) {
    return __uint_as_float((unsigned int)s << 16);
}
static __device__ __forceinline__ float sigm(float x) {
    return __builtin_amdgcn_rcpf(1.0f + __expf(-x));
}
static __device__ __forceinline__ float tanh_(float x) {
    return 1.0f - 2.0f * __builtin_amdgcn_rcpf(1.0f + __expf(2.0f * x));
}

// ---------------------------------------------------------------- embedding
__global__ void embed_kernel(const int* __restrict__ sen, const int* __restrict__ tgt,
                             const float* __restrict__ emb,
                             u16* __restrict__ Xs, u16* __restrict__ Xt)
{
    int row = blockIdx.x;
    int tok; u16* dst;
    if (row < 16384) { tok = sen[row]; dst = Xs + (size_t)row * KP; }
    else             { tok = tgt[row - 16384]; dst = Xt + (size_t)(row - 16384) * KP; }
    const float* src = emb + (size_t)tok * 300;
    for (int k = threadIdx.x; k < KP; k += blockDim.x) {
        float v = (k < 300 && tok != 0) ? src[k] : 0.0f;   // padding_idx=0
        dst[k] = f2bf(v);
    }
}

// ---------------------------------------------------------------- weight prep (all 4 dirs)
__global__ __launch_bounds__(256) void prep_weights_kernel(
    Ptr4 Wih, Ptr4 bih, Ptr4 bhh, u16* __restrict__ WihB, float* __restrict__ biasB)
{
    int dir = blockIdx.y;
    int idx = blockIdx.x * 256 + threadIdx.x;
    if (idx < FH * KP) {
        int row = idx / KP, k = idx - row * KP;
        WihB[(size_t)dir * FH * KP + idx] = (k < 300) ? f2bf(Wih.p[dir][row * 300 + k]) : (u16)0;
    }
    if (idx < FH) biasB[dir * FH + idx] = bih.p[dir][idx] + bhh.p[dir][idx];
}

// ---------------------------------------------------------------- Whh -> i8 row-scaled (all dirs)
__global__ __launch_bounds__(64) void whh_quant_kernel(
    Ptr4 Whh, char* __restrict__ Wq, float* __restrict__ wdq)
{
    int dir = blockIdx.y, row = blockIdx.x, tid = threadIdx.x;
    const float* src = Whh.p[dir] + (size_t)row * HH;
    float m = 0.0f;
    for (int k = tid; k < HH; k += 64) m = fmaxf(m, fabsf(src[k]));
    for (int off = 32; off; off >>= 1) m = fmaxf(m, __shfl_down(m, off));
    m = __shfl(m, 0);
    float qs = (m > 0.0f) ? 127.0f / m : 0.0f;
    char* dst = Wq + (size_t)dir * FH * HH + (size_t)row * HH;
    for (int k = tid; k < HH; k += 64) dst[k] = (char)(int)rintf(src[k] * qs);
    if (tid == 0) wdq[dir * FH + row] = (m > 0.0f) ? m / (127.0f * 127.0f) : 0.0f;
}

// ---------------------------------------------------------------- input GEMM (fused dir-pair)
// One launch covers TWO directions: W has 2048 rows (dir-major), N=2048, NB=32 n-blocks.
// 1D grid, bijective XCD swizzle so each XCD owns a contiguous m-range: the 1.3MB B panel
// stays L2-resident per XCD, A is streamed once. G layout out: [row m][unit*4+gate] bf16.
__global__ __launch_bounds__(256) void input_gemm_kernel(
    const u16* __restrict__ X, const u16* __restrict__ W,
    const float* __restrict__ bias, u16* __restrict__ G, size_t dirStride)
{
    int nwg = gridDim.x;                       // multiple of 8
    int cpx = nwg >> 3;
    int wid = (blockIdx.x & 7) * cpx + (blockIdx.x >> 3);
    int nblk = wid & 31;                       // NB = 32 (N = 2048)
    int mblk = wid >> 5;

    int wave = threadIdx.x >> 6, lane = threadIdx.x & 63;
    int r = lane & 15, quad = lane >> 4;
    int m0 = mblk * 64 + wave * 16;
    int n0 = nblk * 64;
    f32x4 acc[4] = {};
    const u16* xr = X + (size_t)(m0 + r) * KP + quad * 8;
    const u16* wr = W + (size_t)(n0 + r) * KP + quad * 8;
#pragma unroll
    for (int k0 = 0; k0 < KP; k0 += 32) {
        bf16x8 a = *(const bf16x8*)(xr + k0);
#pragma unroll
        for (int j = 0; j < 4; ++j) {
            bf16x8 b = *(const bf16x8*)(wr + (size_t)j * 16 * KP + k0);
            acc[j] = __builtin_amdgcn_mfma_f32_16x16x32_bf16(a, b, acc[j], 0, 0, 0);
        }
    }
#pragma unroll
    for (int j = 0; j < 4; ++j)
#pragma unroll
        for (int reg = 0; reg < 4; ++reg) {
            int row = quad * 4 + reg;
            int n = n0 + j * 16 + r;           // global col in [0,2048)
            int dirb = n >> 10, nn = n & 1023;
            int gate = nn >> 8, unit = nn & 255;
            G[(size_t)dirb * dirStride + (size_t)(m0 + row) * FH + unit * 4 + gate]
                = f2bf(acc[j][reg] + bias[n]);
        }
}

// ---------------------------------------------------------------- LSTM scan
// 32 WGs x 1024 thr (16 waves; 1024-thr WG forces 4 waves/SIMD => 128-reg cap).
// dir = bx>>3, batch chunk = (bx&7)*16. ONE WG holds the entire direction recurrence
// for its 16 batches. Wave w owns units [w*16,w*16+16) x 4 gates = 64 Whh rows:
// Bq[4][8] u64 = 64 regs/lane of i8 B-frags (AGPR; R2 showed VGPR=64 => Bq in AGPRs).
//
// R2 post-mortem: one-barrier structure EXPOSED two VMEM latencies in the per-step
// critical path, because __syncthreads drains vmcnt(0): (a) Hout stores issued right
// before the barrier paid store-ack (~270cy/step); (b) the gv load's MFMA cover shrank
// from 128 to 32 MFMAs. Fix: software-pipeline one full step — prefetch gv(s+1) AND
// store h(s-1) (kept in hreg) at the TOP of step s; both retire under MFMA+gates
// (~2000cy) so the pre-barrier drain is free. gvA/gvB double-buffered registers with
// static indexing via 2-step unroll (rule #20).
// mfma_i32_16x16x32_i8: A lane(m=l&15,k=quad*8+j), B lane(n=l&15,k=quad*8+j),
// D lane(col=l&15,row=quad*4+reg) — all 4 gates of a unit land in one lane.
__global__ __launch_bounds__(1024, 1) void lstm_scan_kernel(
    const char*  __restrict__ WqB,   // [4][1024][256] i8
    const float* __restrict__ wdq,   // [4][1024] dequant scales
    const u16*   __restrict__ Gs,    // [2][16384][1024] bf16 (gate-interleaved, bias folded)
    const u16*   __restrict__ Gt,    // [2][1024][1024] bf16
    float* __restrict__ senH,        // [128][128][512]
    float* __restrict__ tgtH)        // [128][8][512]
{
    const int bx  = blockIdx.x;
    const int dir = bx >> 3;
    const int b0  = (bx & 7) << 4;
    const int T   = (dir < 2) ? 128 : 8;
    const int rev = dir & 1;

    const char* Wq = WqB + (size_t)dir * FH * HH;
    const u16*  G  = (dir < 2) ? (Gs + (size_t)dir * 16384 * FH)
                               : (Gt + (size_t)(dir - 2) * 1024 * FH);
    float* Hout = (dir < 2) ? senH : tgtH;
    const int hofs = rev ? 256 : 0;

    const int tid  = threadIdx.x;
    const int w    = tid >> 6, lane = tid & 63;
    const int r    = lane & 15, quad = lane >> 4;
    const int u    = w * 16 + r;     // this lane's unit

    __shared__ char hb8[2][16][272]; // h as i8, double-buffered (A-operand source)

    // ---- Whh i8 B-frags into registers (persist across all steps)
    // Bq[g][kt]: row = g*256 + u, k-slice = kt*32 + quad*8
    u64 Bq[4][8];
    float dqv[4];
#pragma unroll
    for (int g = 0; g < 4; ++g) {
        int row = g * 256 + u;
        dqv[g] = wdq[dir * FH + row];
#pragma unroll
        for (int kt = 0; kt < 8; ++kt)
            Bq[g][kt] = *(const u64*)(Wq + ((size_t)row << 8) + kt * 32 + quad * 8);
    }

    // ---- zero h(-1) (buffer 0; buffer 1 is written before first read)
    for (int i = tid; i < 2 * 16 * 272; i += 1024) (&hb8[0][0][0])[i] = 0;
    __syncthreads();

    float c[4] = {};      // cell state per batch-row reg
    float hreg[4] = {};   // h(s-1), stored to Hout one step late
    int tprev = 0;

    // ---- prologue: pregates for step 0
    s16x4 gvA[4], gvB[4];
    {
        const int t0 = rev ? (T - 1) : 0;
#pragma unroll
        for (int reg = 0; reg < 4; ++reg)
            gvA[reg] = *(const s16x4*)(G + ((size_t)(b0 + quad * 4 + reg) * T + t0) * FH
                                       + u * 4);
    }

    // One step: prefetch gv(next) + store h(prev) FIRST (retire under MFMA+gates),
    // then MFMA from hb8[cur], then gates -> hreg + hb8[cur^1], then barrier.
    auto body = [&](int cur, s16x4 (&gvU)[4], s16x4 (&gvP)[4],
                    int t, int tn, int doStore) {
#pragma unroll
        for (int reg = 0; reg < 4; ++reg)
            gvP[reg] = *(const s16x4*)(G + ((size_t)(b0 + quad * 4 + reg) * T + tn) * FH
                                       + u * 4);
        if (doStore) {
#pragma unroll
            for (int reg = 0; reg < 4; ++reg)
                Hout[((size_t)(b0 + quad * 4 + reg) * T + tprev) * 512 + hofs + u]
                    = hreg[reg];
        }

        i32x4 acc[4] = {};   // per gate
#pragma unroll
        for (int kt = 0; kt < 8; ++kt) {
            u64 a = *(const u64*)&hb8[cur][r][quad * 8 + kt * 32];
#pragma unroll
            for (int g = 0; g < 4; ++g)
                acc[g] = __builtin_amdgcn_mfma_i32_16x16x32_i8(
                    (long long)a, (long long)Bq[g][kt], acc[g], 0, 0, 0);
        }

#pragma unroll
        for (int reg = 0; reg < 4; ++reg) {
            int bb = quad * 4 + reg;
            float pi = (float)acc[0][reg] * dqv[0] + bf2f((u16)gvU[reg].x);
            float pf = (float)acc[1][reg] * dqv[1] + bf2f((u16)gvU[reg].y);
            float pg = (float)acc[2][reg] * dqv[2] + bf2f((u16)gvU[reg].z);
            float po = (float)acc[3][reg] * dqv[3] + bf2f((u16)gvU[reg].w);
            float ig = sigm(pi), fg = sigm(pf), gg = tanh_(pg), og = sigm(po);
            float cn = fg * c[reg] + ig * gg;
            c[reg] = cn;
            float hn = og * tanh_(cn);
            hb8[cur ^ 1][bb][u] = (char)(int)rintf(hn * 127.0f);
            hreg[reg] = hn;
        }
        tprev = t;
        __syncthreads();   // h(s) visible; gv prefetch + Hout store retired by now
    };

    for (int s2 = 0; s2 < T; s2 += 2) {
        const int tA = rev ? (T - 1 - s2) : s2;
        const int tB = rev ? (T - 2 - s2) : (s2 + 1);
        const int tC = (s2 + 2 < T) ? (rev ? (T - 3 - s2) : (s2 + 2)) : tB;
        body(0, gvA, gvB, tA, tB, s2 > 0);   // even step: reads hb8[0], writes hb8[1]
        body(1, gvB, gvA, tB, tC, 1);        // odd step:  reads hb8[1], writes hb8[0]
    }

    // ---- epilogue: store h(T-1)
#pragma unroll
    for (int reg = 0; reg < 4; ++reg)
        Hout[((size_t)(b0 + quad * 4 + reg) * T + tprev) * 512 + hofs + u] = hreg[reg];
}

// ---------------------------------------------------------------- attention + head
__global__ __launch_bounds__(256) void attn_out_kernel(
    const float* __restrict__ senH, const float* __restrict__ tgtH,
    const float* __restrict__ Wout, const float* __restrict__ bout,
    float* __restrict__ out)
{
    int b = blockIdx.x, tid = threadIdx.x;
    __shared__ float tg[8][512];
    __shared__ float Am[128][9];
    __shared__ float rowm[128][9];
    __shared__ float mcol[8], csum[8], rvec[8], attn[128], score[512], lg[3];

    const float* tgg = tgtH + (size_t)b * 8 * 512;
    for (int i = tid; i < 4096; i += 256) tg[i >> 9][i & 511] = tgg[i];
    __syncthreads();

    {   // A[s][t] = sen_h[b,s,:] . tgt_h[b,t,:]
        int s = tid >> 1, t0 = (tid & 1) * 4;
        const float* sr = senH + ((size_t)b * 128 + s) * 512;
        float d0 = 0, d1 = 0, d2 = 0, d3 = 0;
        for (int h = 0; h < 512; ++h) {
            float x = sr[h];
            d0 += x * tg[t0 + 0][h]; d1 += x * tg[t0 + 1][h];
            d2 += x * tg[t0 + 2][h]; d3 += x * tg[t0 + 3][h];
        }
        Am[s][t0 + 0] = d0; Am[s][t0 + 1] = d1; Am[s][t0 + 2] = d2; Am[s][t0 + 3] = d3;
    }
    __syncthreads();

    if (tid < 8) {  // col-softmax stats over s, per t
        float m = -1e30f;
        for (int s = 0; s < 128; ++s) m = fmaxf(m, Am[s][tid]);
        float sum = 0;
        for (int s = 0; s < 128; ++s) sum += __expf(Am[s][tid] - m);
        mcol[tid] = m; csum[tid] = sum;
    }
    if (tid >= 64 && tid < 192) {  // row softmax per s
        int s = tid - 64;
        float m = -1e30f;
        for (int t = 0; t < 8; ++t) m = fmaxf(m, Am[s][t]);
        float e[8], sum = 0;
        for (int t = 0; t < 8; ++t) { e[t] = __expf(Am[s][t] - m); sum += e[t]; }
        float inv = __builtin_amdgcn_rcpf(sum);
        for (int t = 0; t < 8; ++t) rowm[s][t] = e[t] * inv;
    }
    __syncthreads();
    if (tid < 8) {
        float sum = 0;
        for (int s = 0; s < 128; ++s) sum += rowm[s][tid];
        rvec[tid] = sum * (1.0f / 128.0f);
    }
    __syncthreads();
    if (tid < 128) {
        float a = 0;
        for (int t = 0; t < 8; ++t)
            a += __expf(Am[tid][t] - mcol[t]) / csum[t] * rvec[t];
        attn[tid] = a;
    }
    __syncthreads();
    for (int h = tid; h < 512; h += 256) {
        float acc = 0;
        const float* sp = senH + (size_t)b * 128 * 512 + h;
        for (int s = 0; s < 128; ++s) acc += attn[s] * sp[(size_t)s * 512];
        score[h] = acc;
    }
    __syncthreads();
    if (tid < 3) {
        float acc = bout[tid];
        const float* wr = Wout + tid * 512;
        for (int h = 0; h < 512; ++h) acc += score[h] * wr[h];
        lg[tid] = acc;
    }
    __syncthreads();
    if (tid == 0) {
        float m = fmaxf(lg[0], fmaxf(lg[1], lg[2]));
        float e0 = __expf(lg[0] - m), e1 = __expf(lg[1] - m), e2 = __expf(lg[2] - m);
        float inv = 1.0f / (e0 + e1 + e2);
        out[b * 3 + 0] = e0 * inv; out[b * 3 + 1] = e1 * inv; out[b * 3 + 2] = e2 * inv;
    }
}

// ---------------------------------------------------------------- launch
extern "C" void kernel_launch(void* const* d_in, const int* in_sizes, int n_in,
                              void* d_out, int out_size, void* d_ws, size_t ws_size,
                              hipStream_t stream)
{
    const int*   sen = (const int*)d_in[0];
    const int*   tgt = (const int*)d_in[1];
    const float* emb = (const float*)d_in[2];
    Ptr4 Wih = {{(const float*)d_in[3],  (const float*)d_in[7],
                 (const float*)d_in[11], (const float*)d_in[15]}};
    Ptr4 Whh = {{(const float*)d_in[4],  (const float*)d_in[8],
                 (const float*)d_in[12], (const float*)d_in[16]}};
    Ptr4 bih = {{(const float*)d_in[5],  (const float*)d_in[9],
                 (const float*)d_in[13], (const float*)d_in[17]}};
    Ptr4 bhh = {{(const float*)d_in[6],  (const float*)d_in[10],
                 (const float*)d_in[14], (const float*)d_in[18]}};
    const float* Wout = (const float*)d_in[19];
    const float* bout = (const float*)d_in[20];
    float* out = (float*)d_out;

    char* ws = (char*)d_ws;
    size_t off = 0;
    auto alloc = [&](size_t bytes) -> void* {
        void* p = ws + off; off += (bytes + 255) & ~(size_t)255; return p;
    };
    u16*   Xs    = (u16*)alloc((size_t)16384 * KP * 2);
    u16*   Xt    = (u16*)alloc((size_t)1024 * KP * 2);
    u16*   WihB  = (u16*)alloc((size_t)4 * FH * KP * 2);
    char*  WqB   = (char*)alloc((size_t)4 * FH * HH);
    float* wdq   = (float*)alloc((size_t)4 * FH * 4);
    float* biasB = (float*)alloc((size_t)4 * FH * 4);
    u16*   Gs    = (u16*)alloc((size_t)2 * 16384 * FH * 2);
    u16*   Gt    = (u16*)alloc((size_t)2 * 1024 * FH * 2);
    float* senH  = (float*)alloc((size_t)128 * 128 * 512 * 4);
    float* tgtH  = (float*)alloc((size_t)128 * 8 * 512 * 4);
    (void)ws_size; (void)in_sizes; (void)n_in; (void)out_size;

    embed_kernel<<<17408, 128, 0, stream>>>(sen, tgt, emb, Xs, Xt);
    prep_weights_kernel<<<dim3(1280, 4), 256, 0, stream>>>(Wih, bih, bhh, WihB, biasB);
    whh_quant_kernel<<<dim3(FH, 4), 64, 0, stream>>>(Whh, WqB, wdq);

    // sen: M=16384, N=2048 (dirs 0,1). tgt: M=1024, N=2048 (dirs 2,3).
    input_gemm_kernel<<<8192, 256, 0, stream>>>(Xs, WihB, biasB, Gs,
                                                (size_t)16384 * FH);
    input_gemm_kernel<<<512, 256, 0, stream>>>(Xt, WihB + (size_t)2 * FH * KP,
                                               biasB + 2 * FH, Gt,
                                               (size_t)1024 * FH);

    lstm_scan_kernel<<<32, 1024, 0, stream>>>(WqB, wdq, Gs, Gt, senH, tgtH);
    attn_out_kernel<<<128, 256, 0, stream>>>(senH, tgtH, Wout, bout, out);
}